// Round 12
// baseline (508.552 us; speedup 1.0000x reference)
//
#include <hip/hip_runtime.h>

#define D 64
#define NCLS 10
#define NG 128
#define NBLK 128   // partition blocks for bucket build
#define BSH 7      // bucket shift: 128 nodes/bucket
#define BSZ 128    // nodes per bucket
#define MAXNB 1024 // max buckets (ceil(N/128)=782)

// bf16 helpers (RNE encode, cheap decode)
__device__ __forceinline__ unsigned short f2bf(float v) {
    unsigned b = __float_as_uint(v);
    b += 0x7fff + ((b >> 16) & 1);
    return (unsigned short)(b >> 16);
}
__device__ __forceinline__ float bf2f(unsigned short h) {
    return __uint_as_float(((unsigned)h) << 16);
}

// ---- h_scaled = (x @ W1) * dinv(row) -> bf16, LDS-tiled register-blocked GEMM ----
__global__ __launch_bounds__(256) void k_xw1(const float* __restrict__ x,
                      const float* __restrict__ W1, const float* __restrict__ dinv,
                      int N, ushort4* __restrict__ hs4) {
    __shared__ float wl[D * D];   // W1[k][c]
    __shared__ float xt[64 * D];  // x-tile, row-major [r][k]
    int tid = threadIdx.x;
    const float4* W4 = (const float4*)W1;
    float4* wl4 = (float4*)wl;
#pragma unroll
    for (int i = 0; i < 4; ++i) wl4[i * 256 + tid] = W4[i * 256 + tid];
    int row0 = blockIdx.x * 64;
    const float4* x4 = (const float4*)x;
    float4* xt4 = (float4*)xt;
#pragma unroll
    for (int i = 0; i < 4; ++i) {
        int flat = i * 256 + tid;
        int row = row0 + (flat >> 4);
        float4 v = make_float4(0.f, 0.f, 0.f, 0.f);
        if (row < N) v = x4[(size_t)row * 16 + (flat & 15)];
        xt4[flat] = v;
    }
    __syncthreads();
    int col4 = tid & 15;
    int rowg = tid >> 4;
    float4 acc[4];
#pragma unroll
    for (int i = 0; i < 4; ++i) acc[i] = make_float4(0.f, 0.f, 0.f, 0.f);
#pragma unroll 8
    for (int k = 0; k < D; ++k) {
        float4 wv = *(const float4*)&wl[k * D + col4 * 4];
#pragma unroll
        for (int i = 0; i < 4; ++i) {
            float xv = xt[(rowg * 4 + i) * D + k];
            acc[i].x += xv * wv.x;
            acc[i].y += xv * wv.y;
            acc[i].z += xv * wv.z;
            acc[i].w += xv * wv.w;
        }
    }
#pragma unroll
    for (int i = 0; i < 4; ++i) {
        int row = row0 + rowg * 4 + i;
        if (row >= N) continue;
        float d = dinv[row];
        ushort4 o;
        o.x = f2bf(acc[i].x * d);
        o.y = f2bf(acc[i].y * d);
        o.z = f2bf(acc[i].z * d);
        o.w = f2bf(acc[i].w * d);
        hs4[(size_t)row * 16 + col4] = o;
    }
}

// ---- bucket build pass 1: per-block histogram of dst>>BSH (+ zero gsum/gcnt) ----
// blkCount layout: [blk][bucket] (transposed for coalesced bbase/bplace access)
__global__ __launch_bounds__(256) void k_bcount(const int* __restrict__ dst, int E,
                                                int NB, int* __restrict__ blkCount,
                                                float* __restrict__ gsum,
                                                float* __restrict__ gcnt) {
    __shared__ int cnt[MAXNB];
    int tid = threadIdx.x;
    int blk = blockIdx.x;
    int gt = blk * 256 + tid;
    if (gt < NG * D) gsum[gt] = 0.f;
    if (gt < NG) gcnt[gt] = 0.f;
    for (int b = tid; b < NB; b += 256) cnt[b] = 0;
    __syncthreads();
    int ch = (E + NBLK - 1) / NBLK;
    int beg = blk * ch, end = min(beg + ch, E);
    for (int i = beg + tid; i < end; i += 256) atomicAdd(&cnt[dst[i] >> BSH], 1);
    __syncthreads();
    for (int b = tid; b < NB; b += 256) blkCount[(size_t)blk * MAXNB + b] = cnt[b];
}

// ---- bucket build pass 2: totals -> exclusive bases, per-(block,bucket) bases ----
__global__ __launch_bounds__(1024) void k_bbase(int* __restrict__ blkCount, int NB, int E,
                                                int* __restrict__ bucketBase) {
    __shared__ int sd[1024];
    int tid = threadIdx.x;
    int tot = 0;
    if (tid < NB)
        for (int blk = 0; blk < NBLK; ++blk) tot += blkCount[(size_t)blk * MAXNB + tid];
    sd[tid] = (tid < NB) ? tot : 0;
    __syncthreads();
    for (int off = 1; off < 1024; off <<= 1) {
        int tmp = (tid >= off) ? sd[tid - off] : 0;
        __syncthreads();
        sd[tid] += tmp;
        __syncthreads();
    }
    if (tid < NB) {
        int run = (tid == 0) ? 0 : sd[tid - 1];
        bucketBase[tid] = run;
        for (int blk = 0; blk < NBLK; ++blk) {
            int t = blkCount[(size_t)blk * MAXNB + tid];
            blkCount[(size_t)blk * MAXNB + tid] = run;
            run += t;
        }
    }
    if (tid == 0) bucketBase[NB] = E;
}

// ---- bucket build pass 3: place packed (src<<BSH)|dstLocal grouped by bucket ----
__global__ __launch_bounds__(256) void k_bplace(const int* __restrict__ src,
                                                const int* __restrict__ dst, int E,
                                                int NB, const int* __restrict__ blkCount,
                                                int* __restrict__ e2p) {
    __shared__ int cur[MAXNB];
    int tid = threadIdx.x;
    int blk = blockIdx.x;
    for (int b = tid; b < NB; b += 256) cur[b] = blkCount[(size_t)blk * MAXNB + b];
    __syncthreads();
    int ch = (E + NBLK - 1) / NBLK;
    int beg = blk * ch, end = min(beg + ch, E);
    for (int i = beg + tid; i < end; i += 256) {
        int s = src[i], t = dst[i];
        int pos = atomicAdd(&cur[t >> BSH], 1);
        e2p[pos] = (s << BSH) | (t & (BSZ - 1));
    }
}

// ---- per-bucket degree -> dinv (before k_xw1 which folds dinv into hs4) ----
__global__ __launch_bounds__(256) void k_deginv(const int* __restrict__ e2p,
                                                const int* __restrict__ bucketBase,
                                                int N, float* __restrict__ dinv) {
    __shared__ int cnt[BSZ];
    int tid = threadIdx.x;
    if (tid < BSZ) cnt[tid] = 0;
    __syncthreads();
    int bb = bucketBase[blockIdx.x];
    int end = bucketBase[blockIdx.x + 1];
    for (int i = bb + tid; i < end; i += 256) atomicAdd(&cnt[e2p[i] & (BSZ - 1)], 1);
    __syncthreads();
    int node = (blockIdx.x << BSH) + tid;
    if (tid < BSZ && node < N) dinv[node] = rsqrtf((float)(cnt[tid] + 1));
}

// ---- fused bucket aggregate + relu + mean-pool: block per 128-node bucket ----
// 16-lane groups gather hs4[src] rows from unordered e2p, ds_add_f32 into LDS;
// then self-loop + dinv/bias/relu + sorted-batch pool flush, all in one kernel.
__global__ __launch_bounds__(256) void k_bagg(
    const ushort4* __restrict__ hs4, const float* __restrict__ dinv,
    const int* __restrict__ e2p, const int* __restrict__ bucketBase,
    const int* __restrict__ batch, const float* __restrict__ b1,
    int N, float* __restrict__ gsum, float* __restrict__ gcnt) {
    __shared__ float acc[BSZ * D];  // 32 KB fp32 accumulator
    int tid = threadIdx.x;
    float4* accv = (float4*)acc;
#pragma unroll
    for (int i = 0; i < (BSZ * D / 4) / 256; ++i)
        accv[i * 256 + tid] = make_float4(0.f, 0.f, 0.f, 0.f);
    __syncthreads();
    int bb = bucketBase[blockIdx.x];
    int end = bucketBase[blockIdx.x + 1];
    int q = tid >> 4;       // 16 groups
    int c4 = tid & 15;      // channel quad
    int i = bb + q;
    for (; i + 16 < end; i += 32) {  // 2 gathers in flight per group
        int p0 = e2p[i];
        int p1 = e2p[i + 16];
        ushort4 u0 = hs4[(size_t)(p0 >> BSH) * 16 + c4];
        ushort4 u1 = hs4[(size_t)(p1 >> BSH) * 16 + c4];
        float* a0 = &acc[(p0 & (BSZ - 1)) * D + c4 * 4];
        float* a1 = &acc[(p1 & (BSZ - 1)) * D + c4 * 4];
        atomicAdd(a0 + 0, bf2f(u0.x)); atomicAdd(a0 + 1, bf2f(u0.y));
        atomicAdd(a0 + 2, bf2f(u0.z)); atomicAdd(a0 + 3, bf2f(u0.w));
        atomicAdd(a1 + 0, bf2f(u1.x)); atomicAdd(a1 + 1, bf2f(u1.y));
        atomicAdd(a1 + 2, bf2f(u1.z)); atomicAdd(a1 + 3, bf2f(u1.w));
    }
    if (i < end) {
        int p = e2p[i];
        ushort4 u = hs4[(size_t)(p >> BSH) * 16 + c4];
        float* a = &acc[(p & (BSZ - 1)) * D + c4 * 4];
        atomicAdd(a + 0, bf2f(u.x)); atomicAdd(a + 1, bf2f(u.y));
        atomicAdd(a + 2, bf2f(u.z)); atomicAdd(a + 3, bf2f(u.w));
    }
    __syncthreads();
    // self-loop + scale + relu + pool: group q owns 8 consecutive nodes
    int node0 = (blockIdx.x << BSH) + q * 8;
    float4 b = ((const float4*)b1)[c4];
    float4 ps = make_float4(0.f, 0.f, 0.f, 0.f);
    float cntf = 0.f;
    int cur_g = -1;
#pragma unroll
    for (int nn = 0; nn < 8; ++nn) {
        int node = node0 + nn;
        if (node >= N) break;
        int g = batch[node];
        if (g != cur_g) {
            if (cur_g >= 0) {
                float* gs = &gsum[cur_g * D + c4 * 4];
                atomicAdd(gs + 0, ps.x); atomicAdd(gs + 1, ps.y);
                atomicAdd(gs + 2, ps.z); atomicAdd(gs + 3, ps.w);
                if (c4 == 0) atomicAdd(&gcnt[cur_g], cntf);
            }
            ps = make_float4(0.f, 0.f, 0.f, 0.f);
            cntf = 0.f;
            cur_g = g;
        }
        ushort4 su = hs4[(size_t)node * 16 + c4];  // self-loop row (already *dinv)
        float d = dinv[node];
        const float* ap = &acc[(q * 8 + nn) * D + c4 * 4];
        ps.x += fmaxf((ap[0] + bf2f(su.x)) * d + b.x, 0.f);
        ps.y += fmaxf((ap[1] + bf2f(su.y)) * d + b.y, 0.f);
        ps.z += fmaxf((ap[2] + bf2f(su.z)) * d + b.z, 0.f);
        ps.w += fmaxf((ap[3] + bf2f(su.w)) * d + b.w, 0.f);
        cntf += 1.f;
    }
    if (cur_g >= 0) {
        float* gs = &gsum[cur_g * D + c4 * 4];
        atomicAdd(gs + 0, ps.x); atomicAdd(gs + 1, ps.y);
        atomicAdd(gs + 2, ps.z); atomicAdd(gs + 3, ps.w);
        if (c4 == 0) atomicAdd(&gcnt[cur_g], cntf);
    }
}

// ---- head ----
__global__ void k_head(const float* __restrict__ gsum, const float* __restrict__ gcnt,
                       const float* __restrict__ W2, const float* __restrict__ b2,
                       float* __restrict__ out) {
    int g = threadIdx.x;
    if (g >= NG) return;
    float cnt = gcnt[g];
    cnt = cnt > 1.f ? cnt : 1.f;
    float inv = 1.f / cnt;
    float logits[NCLS];
#pragma unroll
    for (int c = 0; c < NCLS; ++c) logits[c] = b2[c];
    for (int k = 0; k < D; ++k) {
        float hk = gsum[g * D + k] * inv;
#pragma unroll
        for (int c = 0; c < NCLS; ++c) logits[c] += hk * W2[k * NCLS + c];
    }
    float m = logits[0];
#pragma unroll
    for (int c = 1; c < NCLS; ++c) m = fmaxf(m, logits[c]);
    float se = 0.f;
#pragma unroll
    for (int c = 0; c < NCLS; ++c) se += expf(logits[c] - m);
    float lse = m + logf(se);
#pragma unroll
    for (int c = 0; c < NCLS; ++c) out[g * NCLS + c] = logits[c] - lse;
}

static inline size_t pad256(size_t x) { return (x + 255) & ~(size_t)255; }

extern "C" void kernel_launch(void* const* d_in, const int* in_sizes, int n_in,
                              void* d_out, int out_size, void* d_ws, size_t ws_size,
                              hipStream_t stream) {
    const float* x     = (const float*)d_in[0];
    const int*   ei    = (const int*)d_in[1];   // [2, E]: src row then dst row
    const int*   batch = (const int*)d_in[2];
    const float* W1    = (const float*)d_in[3];
    const float* b1    = (const float*)d_in[4];
    const float* W2    = (const float*)d_in[5];
    const float* b2    = (const float*)d_in[6];
    float* out = (float*)d_out;

    const int N = in_sizes[0] / D;   // 100000
    const int E = in_sizes[1] / 2;   // 1000000
    const int NB = (N + BSZ - 1) >> BSH;  // 782 buckets

    char* w = (char*)d_ws;
    ushort4* hs4      = (ushort4*)w; w += pad256((size_t)N * D * 2);
    float* dinv       = (float*)w;  w += pad256((size_t)N * 4);
    int*   e2p        = (int*)w;    w += pad256((size_t)E * 4);
    int*   blkCount   = (int*)w;    w += pad256((size_t)NBLK * MAXNB * 4);
    int*   bucketBase = (int*)w;    w += pad256((size_t)(MAXNB + 1) * 4);
    float* gsum       = (float*)w;  w += pad256((size_t)NG * D * 4);
    float* gcnt       = (float*)w;  w += pad256((size_t)NG * 4);

    const int* e_src = ei;
    const int* e_dst = ei + E;

    k_bcount<<<NBLK, 256, 0, stream>>>(e_dst, E, NB, blkCount, gsum, gcnt);
    k_bbase<<<1, 1024, 0, stream>>>(blkCount, NB, E, bucketBase);
    k_bplace<<<NBLK, 256, 0, stream>>>(e_src, e_dst, E, NB, blkCount, e2p);
    k_deginv<<<NB, 256, 0, stream>>>(e2p, bucketBase, N, dinv);

    k_xw1<<<(N + 63) / 64, 256, 0, stream>>>(x, W1, dinv, N, hs4);

    k_bagg<<<NB, 256, 0, stream>>>(hs4, dinv, e2p, bucketBase, batch, b1,
                                   N, gsum, gcnt);

    k_head<<<1, 128, 0, stream>>>(gsum, gcnt, W2, b2, out);
}

// Round 13
// 137.697 us; speedup vs baseline: 3.6933x; 3.6933x over previous
//
#include <hip/hip_runtime.h>

#define D 64
#define NCLS 10
#define NG 128
#define NPW 64    // nodes per wave in k_pool
#define NBLK 128  // partition blocks for bucket build
#define MAXNB 512 // max coarse buckets (N/256)

// bf16 helpers (RNE encode, cheap decode)
__device__ __forceinline__ unsigned short f2bf(float v) {
    unsigned b = __float_as_uint(v);
    b += 0x7fff + ((b >> 16) & 1);
    return (unsigned short)(b >> 16);
}
__device__ __forceinline__ float bf2f(unsigned short h) {
    return __uint_as_float(((unsigned)h) << 16);
}

// ---- h_scaled = (x @ W1) * dinv(row) -> bf16, LDS-tiled register-blocked GEMM ----
__global__ __launch_bounds__(256) void k_xw1(const float* __restrict__ x,
                      const float* __restrict__ W1, const float* __restrict__ dinv,
                      int N, ushort4* __restrict__ hs4) {
    __shared__ float wl[D * D];   // W1[k][c]
    __shared__ float xt[64 * D];  // x-tile, row-major [r][k]
    int tid = threadIdx.x;
    const float4* W4 = (const float4*)W1;
    float4* wl4 = (float4*)wl;
#pragma unroll
    for (int i = 0; i < 4; ++i) wl4[i * 256 + tid] = W4[i * 256 + tid];
    int row0 = blockIdx.x * 64;
    const float4* x4 = (const float4*)x;
    float4* xt4 = (float4*)xt;
#pragma unroll
    for (int i = 0; i < 4; ++i) {
        int flat = i * 256 + tid;
        int row = row0 + (flat >> 4);
        float4 v = make_float4(0.f, 0.f, 0.f, 0.f);
        if (row < N) v = x4[(size_t)row * 16 + (flat & 15)];
        xt4[flat] = v;
    }
    __syncthreads();
    int col4 = tid & 15;
    int rowg = tid >> 4;
    float4 acc[4];
#pragma unroll
    for (int i = 0; i < 4; ++i) acc[i] = make_float4(0.f, 0.f, 0.f, 0.f);
#pragma unroll 8
    for (int k = 0; k < D; ++k) {
        float4 wv = *(const float4*)&wl[k * D + col4 * 4];
#pragma unroll
        for (int i = 0; i < 4; ++i) {
            float xv = xt[(rowg * 4 + i) * D + k];
            acc[i].x += xv * wv.x;
            acc[i].y += xv * wv.y;
            acc[i].z += xv * wv.z;
            acc[i].w += xv * wv.w;
        }
    }
#pragma unroll
    for (int i = 0; i < 4; ++i) {
        int row = row0 + rowg * 4 + i;
        if (row >= N) continue;
        float d = dinv[row];
        ushort4 o;
        o.x = f2bf(acc[i].x * d);
        o.y = f2bf(acc[i].y * d);
        o.z = f2bf(acc[i].z * d);
        o.w = f2bf(acc[i].w * d);
        hs4[(size_t)row * 16 + col4] = o;
    }
}

// ---- bucket build pass 1: per-block histogram of dst>>8 (+ zero gsum/gcnt) ----
__global__ __launch_bounds__(256) void k_bcount(const int* __restrict__ dst, int E,
                                                int NB, int* __restrict__ blkCount,
                                                float* __restrict__ gsum,
                                                float* __restrict__ gcnt) {
    __shared__ int cnt[MAXNB];
    int tid = threadIdx.x;
    int blk = blockIdx.x;
    int gt = blk * 256 + tid;
    if (gt < NG * D) gsum[gt] = 0.f;
    if (gt < NG) gcnt[gt] = 0.f;
    for (int b = tid; b < NB; b += 256) cnt[b] = 0;
    __syncthreads();
    int ch = (E + NBLK - 1) / NBLK;
    int beg = blk * ch, end = min(beg + ch, E);
    for (int i = beg + tid; i < end; i += 256) atomicAdd(&cnt[dst[i] >> 8], 1);
    __syncthreads();
    for (int b = tid; b < NB; b += 256) blkCount[b * NBLK + blk] = cnt[b];
}

// ---- bucket build pass 2: totals -> exclusive bases, per-(bucket,block) bases ----
__global__ __launch_bounds__(512) void k_bbase(int* __restrict__ blkCount, int NB, int E,
                                               int* __restrict__ bucketBase) {
    __shared__ int sd[512];
    int tid = threadIdx.x;
    int4 c[NBLK / 4];
    int tot = 0;
    if (tid < NB) {
        const int4* p = (const int4*)&blkCount[tid * NBLK];
#pragma unroll
        for (int j = 0; j < NBLK / 4; ++j) {
            c[j] = p[j];
            tot += c[j].x + c[j].y + c[j].z + c[j].w;
        }
    }
    sd[tid] = (tid < NB) ? tot : 0;
    __syncthreads();
    for (int off = 1; off < 512; off <<= 1) {
        int tmp = (tid >= off) ? sd[tid - off] : 0;
        __syncthreads();
        sd[tid] += tmp;
        __syncthreads();
    }
    if (tid < NB) {
        int run = (tid == 0) ? 0 : sd[tid - 1];
        bucketBase[tid] = run;
        int4* p = (int4*)&blkCount[tid * NBLK];
#pragma unroll
        for (int j = 0; j < NBLK / 4; ++j) {
            int t0 = c[j].x; c[j].x = run; run += t0;
            int t1 = c[j].y; c[j].y = run; run += t1;
            int t2 = c[j].z; c[j].z = run; run += t2;
            int t3 = c[j].w; c[j].w = run; run += t3;
            p[j] = c[j];
        }
    }
    if (tid == 0) bucketBase[NB] = E;
}

// ---- bucket build pass 3: place packed (src<<8)|dstLocal grouped by bucket ----
__global__ __launch_bounds__(256) void k_bplace(const int* __restrict__ src,
                                                const int* __restrict__ dst, int E,
                                                int NB, const int* __restrict__ blkCount,
                                                int* __restrict__ e2p) {
    __shared__ int cur[MAXNB];
    int tid = threadIdx.x;
    int blk = blockIdx.x;
    for (int b = tid; b < NB; b += 256) cur[b] = blkCount[b * NBLK + blk];
    __syncthreads();
    int ch = (E + NBLK - 1) / NBLK;
    int beg = blk * ch, end = min(beg + ch, E);
    for (int i = beg + tid; i < end; i += 256) {
        int s = src[i], t = dst[i];
        int pos = atomicAdd(&cur[t >> 8], 1);
        e2p[pos] = (s << 8) | (t & 255);
    }
}

// ---- fused CSR finalize: per-bucket histogram+scan -> rowptr & dinv, scatter srcs ----
__global__ __launch_bounds__(256) void k_csrdeg(const int* __restrict__ e2p,
                                                const int* __restrict__ bucketBase,
                                                int N, int E,
                                                int* __restrict__ rowptr,
                                                float* __restrict__ dinv,
                                                int* __restrict__ srcs) {
    __shared__ int cnt[256];
    __shared__ int sd[256];
    __shared__ int cur[256];
    int tid = threadIdx.x;
    int node0 = blockIdx.x << 8;
    int bb = bucketBase[blockIdx.x];
    int end = bucketBase[blockIdx.x + 1];
    cnt[tid] = 0;
    __syncthreads();
    for (int i = bb + tid; i < end; i += 256) atomicAdd(&cnt[e2p[i] & 255], 1);
    __syncthreads();
    sd[tid] = cnt[tid];
    __syncthreads();
    for (int off = 1; off < 256; off <<= 1) {
        int tmp = (tid >= off) ? sd[tid - off] : 0;
        __syncthreads();
        sd[tid] += tmp;
        __syncthreads();
    }
    int excl = (tid == 0) ? 0 : sd[tid - 1];
    int node = node0 + tid;
    if (node < N) {
        rowptr[node] = bb + excl;
        dinv[node] = rsqrtf((float)(cnt[tid] + 1));
    }
    cur[tid] = bb + excl;
    if (blockIdx.x == 0 && tid == 0) rowptr[N] = E;
    __syncthreads();
    for (int i = bb + tid; i < end; i += 256) {
        int p = e2p[i];
        int pos = atomicAdd(&cur[p & 255], 1);
        srcs[pos] = p >> 8;
    }
}

// ---- gather-aggregate: one 16-lane group per node (4 nodes/wave), 4-deep MLP ----
__global__ void k_gather(const ushort4* __restrict__ hs4, const float* __restrict__ dinv,
                         const int* __restrict__ rowptr, const int* __restrict__ srcs,
                         const float* __restrict__ b1, int N,
                         unsigned long long* __restrict__ r4) {
    int node = (blockIdx.x * blockDim.x + threadIdx.x) >> 4;
    int c4 = threadIdx.x & 15;
    if (node >= N) return;
    int begin = rowptr[node];
    int end = rowptr[node + 1];
    // self-loop (already *dinv[node])
    ushort4 u = hs4[(size_t)node * 16 + c4];
    float4 sum = make_float4(bf2f(u.x), bf2f(u.y), bf2f(u.z), bf2f(u.w));
    int k = begin;
    for (; k + 3 < end; k += 4) {  // four independent gathers in flight
        int s0 = srcs[k];
        int s1 = srcs[k + 1];
        int s2 = srcs[k + 2];
        int s3 = srcs[k + 3];
        ushort4 u0 = hs4[(size_t)s0 * 16 + c4];
        ushort4 u1 = hs4[(size_t)s1 * 16 + c4];
        ushort4 u2 = hs4[(size_t)s2 * 16 + c4];
        ushort4 u3 = hs4[(size_t)s3 * 16 + c4];
        sum.x += (bf2f(u0.x) + bf2f(u1.x)) + (bf2f(u2.x) + bf2f(u3.x));
        sum.y += (bf2f(u0.y) + bf2f(u1.y)) + (bf2f(u2.y) + bf2f(u3.y));
        sum.z += (bf2f(u0.z) + bf2f(u1.z)) + (bf2f(u2.z) + bf2f(u3.z));
        sum.w += (bf2f(u0.w) + bf2f(u1.w)) + (bf2f(u2.w) + bf2f(u3.w));
    }
    for (; k < end; ++k) {
        int s = srcs[k];
        ushort4 uu = hs4[(size_t)s * 16 + c4];
        sum.x += bf2f(uu.x); sum.y += bf2f(uu.y);
        sum.z += bf2f(uu.z); sum.w += bf2f(uu.w);
    }
    float d = dinv[node];
    float4 b = ((const float4*)b1)[c4];
    unsigned long long ox = f2bf(fmaxf(sum.x * d + b.x, 0.f));
    unsigned long long oy = f2bf(fmaxf(sum.y * d + b.y, 0.f));
    unsigned long long oz = f2bf(fmaxf(sum.z * d + b.z, 0.f));
    unsigned long long ow = f2bf(fmaxf(sum.w * d + b.w, 0.f));
    r4[(size_t)node * 16 + c4] = ox | (oy << 16) | (oz << 32) | (ow << 48);
}

// ---- mean-pool: sorted-batch run accumulation (bf16 in, fp32 accum) ----
__global__ void k_pool(const unsigned long long* __restrict__ r4,
                       const int* __restrict__ batch,
                       int N, float* __restrict__ gsum, float* __restrict__ gcnt) {
    int wid = (blockIdx.x * blockDim.x + threadIdx.x) >> 6;
    int lane = threadIdx.x & 63;
    int sub = lane >> 4;
    int c4  = lane & 15;
    int start = wid * NPW;
    if (start >= N) return;
    int end = min(start + NPW, N);
    float4 sum = make_float4(0.f, 0.f, 0.f, 0.f);
    float cnt = 0.f;
    int cur_g = -1;
    for (int i = start + sub; i < end; i += 4) {
        int g = batch[i];
        if (g != cur_g) {
            if (cur_g >= 0) {
                float* gs = &gsum[cur_g * D + c4 * 4];
                atomicAdd(gs + 0, sum.x);
                atomicAdd(gs + 1, sum.y);
                atomicAdd(gs + 2, sum.z);
                atomicAdd(gs + 3, sum.w);
                if (c4 == 0) atomicAdd(&gcnt[cur_g], cnt);
            }
            sum = make_float4(0.f, 0.f, 0.f, 0.f);
            cnt = 0.f;
            cur_g = g;
        }
        unsigned long long pk = r4[(size_t)i * 16 + c4];
        unsigned lo = (unsigned)pk;
        unsigned hi = (unsigned)(pk >> 32);
        sum.x += __uint_as_float(lo << 16);
        sum.y += __uint_as_float(lo & 0xffff0000u);
        sum.z += __uint_as_float(hi << 16);
        sum.w += __uint_as_float(hi & 0xffff0000u);
        cnt += 1.f;
    }
    if (cur_g >= 0) {
        float* gs = &gsum[cur_g * D + c4 * 4];
        atomicAdd(gs + 0, sum.x);
        atomicAdd(gs + 1, sum.y);
        atomicAdd(gs + 2, sum.z);
        atomicAdd(gs + 3, sum.w);
        if (c4 == 0) atomicAdd(&gcnt[cur_g], cnt);
    }
}

// ---- head ----
__global__ void k_head(const float* __restrict__ gsum, const float* __restrict__ gcnt,
                       const float* __restrict__ W2, const float* __restrict__ b2,
                       float* __restrict__ out) {
    int g = threadIdx.x;
    if (g >= NG) return;
    float cnt = gcnt[g];
    cnt = cnt > 1.f ? cnt : 1.f;
    float inv = 1.f / cnt;
    float logits[NCLS];
#pragma unroll
    for (int c = 0; c < NCLS; ++c) logits[c] = b2[c];
    for (int k = 0; k < D; ++k) {
        float hk = gsum[g * D + k] * inv;
#pragma unroll
        for (int c = 0; c < NCLS; ++c) logits[c] += hk * W2[k * NCLS + c];
    }
    float m = logits[0];
#pragma unroll
    for (int c = 1; c < NCLS; ++c) m = fmaxf(m, logits[c]);
    float se = 0.f;
#pragma unroll
    for (int c = 0; c < NCLS; ++c) se += expf(logits[c] - m);
    float lse = m + logf(se);
#pragma unroll
    for (int c = 0; c < NCLS; ++c) out[g * NCLS + c] = logits[c] - lse;
}

static inline size_t pad256(size_t x) { return (x + 255) & ~(size_t)255; }

extern "C" void kernel_launch(void* const* d_in, const int* in_sizes, int n_in,
                              void* d_out, int out_size, void* d_ws, size_t ws_size,
                              hipStream_t stream) {
    const float* x     = (const float*)d_in[0];
    const int*   ei    = (const int*)d_in[1];   // [2, E]: src row then dst row
    const int*   batch = (const int*)d_in[2];
    const float* W1    = (const float*)d_in[3];
    const float* b1    = (const float*)d_in[4];
    const float* W2    = (const float*)d_in[5];
    const float* b2    = (const float*)d_in[6];
    float* out = (float*)d_out;

    const int N = in_sizes[0] / D;   // 100000
    const int E = in_sizes[1] / 2;   // 1000000
    const int NB = (N + 255) >> 8;   // 391 coarse buckets

    char* w = (char*)d_ws;
    ushort4* hs4      = (ushort4*)w; w += pad256((size_t)N * D * 2);
    unsigned long long* r4 = (unsigned long long*)w; w += pad256((size_t)N * D * 2);
    float* dinv       = (float*)w;  w += pad256((size_t)N * 4);
    int*   rowptr     = (int*)w;    w += pad256((size_t)(N + 1) * 4);
    int*   srcs       = (int*)w;    w += pad256((size_t)E * 4);
    int*   e2p        = (int*)w;    w += pad256((size_t)E * 4);
    int*   blkCount   = (int*)w;    w += pad256((size_t)MAXNB * NBLK * 4);
    int*   bucketBase = (int*)w;    w += pad256((size_t)(MAXNB + 1) * 4);
    float* gsum       = (float*)w;  w += pad256((size_t)NG * D * 4);
    float* gcnt       = (float*)w;  w += pad256((size_t)NG * 4);

    const int* e_src = ei;
    const int* e_dst = ei + E;

    k_bcount<<<NBLK, 256, 0, stream>>>(e_dst, E, NB, blkCount, gsum, gcnt);
    k_bbase<<<1, 512, 0, stream>>>(blkCount, NB, E, bucketBase);
    k_bplace<<<NBLK, 256, 0, stream>>>(e_src, e_dst, E, NB, blkCount, e2p);
    k_csrdeg<<<NB, 256, 0, stream>>>(e2p, bucketBase, N, E, rowptr, dinv, srcs);

    k_xw1<<<(N + 63) / 64, 256, 0, stream>>>(x, W1, dinv, N, hs4);

    {
        long long threads = (long long)N * 16;
        int blocks = (int)((threads + 255) / 256);
        k_gather<<<blocks, 256, 0, stream>>>(hs4, dinv, rowptr, srcs, b1, N, r4);
    }
    {
        int waves = (N + NPW - 1) / NPW;
        long long threads = (long long)waves * 64;
        int blocks = (int)((threads + 255) / 256);
        k_pool<<<blocks, 256, 0, stream>>>(r4, batch, N, gsum, gcnt);
    }
    k_head<<<1, 128, 0, stream>>>(gsum, gcnt, W2, b2, out);
}

// Round 14
// 115.309 us; speedup vs baseline: 4.4103x; 1.1942x over previous
//
#include <hip/hip_runtime.h>

#define D 64
#define NCLS 10
#define NG 128
#define NBLK 128  // partition blocks for bucket build
#define MAXNB 512 // max coarse buckets (N/256)
#define TILES 4   // 16-node tiles per k_gpool block (64 nodes/block)

// bf16 helpers (RNE encode, cheap decode)
__device__ __forceinline__ unsigned short f2bf(float v) {
    unsigned b = __float_as_uint(v);
    b += 0x7fff + ((b >> 16) & 1);
    return (unsigned short)(b >> 16);
}
__device__ __forceinline__ float bf2f(unsigned short h) {
    return __uint_as_float(((unsigned)h) << 16);
}

// ---- h_scaled = (x @ W1) * dinv(row) -> bf16, LDS-tiled register-blocked GEMM ----
__global__ __launch_bounds__(256) void k_xw1(const float* __restrict__ x,
                      const float* __restrict__ W1, const float* __restrict__ dinv,
                      int N, ushort4* __restrict__ hs4) {
    __shared__ float wl[D * D];   // W1[k][c]
    __shared__ float xt[64 * D];  // x-tile, row-major [r][k]
    int tid = threadIdx.x;
    const float4* W4 = (const float4*)W1;
    float4* wl4 = (float4*)wl;
#pragma unroll
    for (int i = 0; i < 4; ++i) wl4[i * 256 + tid] = W4[i * 256 + tid];
    int row0 = blockIdx.x * 64;
    const float4* x4 = (const float4*)x;
    float4* xt4 = (float4*)xt;
#pragma unroll
    for (int i = 0; i < 4; ++i) {
        int flat = i * 256 + tid;
        int row = row0 + (flat >> 4);
        float4 v = make_float4(0.f, 0.f, 0.f, 0.f);
        if (row < N) v = x4[(size_t)row * 16 + (flat & 15)];
        xt4[flat] = v;
    }
    __syncthreads();
    int col4 = tid & 15;
    int rowg = tid >> 4;
    float4 acc[4];
#pragma unroll
    for (int i = 0; i < 4; ++i) acc[i] = make_float4(0.f, 0.f, 0.f, 0.f);
#pragma unroll 8
    for (int k = 0; k < D; ++k) {
        float4 wv = *(const float4*)&wl[k * D + col4 * 4];
#pragma unroll
        for (int i = 0; i < 4; ++i) {
            float xv = xt[(rowg * 4 + i) * D + k];
            acc[i].x += xv * wv.x;
            acc[i].y += xv * wv.y;
            acc[i].z += xv * wv.z;
            acc[i].w += xv * wv.w;
        }
    }
#pragma unroll
    for (int i = 0; i < 4; ++i) {
        int row = row0 + rowg * 4 + i;
        if (row >= N) continue;
        float d = dinv[row];
        ushort4 o;
        o.x = f2bf(acc[i].x * d);
        o.y = f2bf(acc[i].y * d);
        o.z = f2bf(acc[i].z * d);
        o.w = f2bf(acc[i].w * d);
        hs4[(size_t)row * 16 + col4] = o;
    }
}

// ---- bucket build pass 1: per-block histogram of dst>>8 (+ zero gsum/gcnt) ----
__global__ __launch_bounds__(256) void k_bcount(const int* __restrict__ dst, int E,
                                                int NB, int* __restrict__ blkCount,
                                                float* __restrict__ gsum,
                                                float* __restrict__ gcnt) {
    __shared__ int cnt[MAXNB];
    int tid = threadIdx.x;
    int blk = blockIdx.x;
    int gt = blk * 256 + tid;
    if (gt < NG * D) gsum[gt] = 0.f;
    if (gt < NG) gcnt[gt] = 0.f;
    for (int b = tid; b < NB; b += 256) cnt[b] = 0;
    __syncthreads();
    int ch = (E + NBLK - 1) / NBLK;
    int beg = blk * ch, end = min(beg + ch, E);
    for (int i = beg + tid; i < end; i += 256) atomicAdd(&cnt[dst[i] >> 8], 1);
    __syncthreads();
    for (int b = tid; b < NB; b += 256) blkCount[b * NBLK + blk] = cnt[b];
}

// ---- bucket build pass 2: totals -> exclusive bases, per-(bucket,block) bases ----
__global__ __launch_bounds__(512) void k_bbase(int* __restrict__ blkCount, int NB, int E,
                                               int* __restrict__ bucketBase) {
    __shared__ int sd[512];
    int tid = threadIdx.x;
    int4 c[NBLK / 4];
    int tot = 0;
    if (tid < NB) {
        const int4* p = (const int4*)&blkCount[tid * NBLK];
#pragma unroll
        for (int j = 0; j < NBLK / 4; ++j) {
            c[j] = p[j];
            tot += c[j].x + c[j].y + c[j].z + c[j].w;
        }
    }
    sd[tid] = (tid < NB) ? tot : 0;
    __syncthreads();
    for (int off = 1; off < 512; off <<= 1) {
        int tmp = (tid >= off) ? sd[tid - off] : 0;
        __syncthreads();
        sd[tid] += tmp;
        __syncthreads();
    }
    if (tid < NB) {
        int run = (tid == 0) ? 0 : sd[tid - 1];
        bucketBase[tid] = run;
        int4* p = (int4*)&blkCount[tid * NBLK];
#pragma unroll
        for (int j = 0; j < NBLK / 4; ++j) {
            int t0 = c[j].x; c[j].x = run; run += t0;
            int t1 = c[j].y; c[j].y = run; run += t1;
            int t2 = c[j].z; c[j].z = run; run += t2;
            int t3 = c[j].w; c[j].w = run; run += t3;
            p[j] = c[j];
        }
    }
    if (tid == 0) bucketBase[NB] = E;
}

// ---- bucket build pass 3: place packed (src<<8)|dstLocal grouped by bucket ----
__global__ __launch_bounds__(256) void k_bplace(const int* __restrict__ src,
                                                const int* __restrict__ dst, int E,
                                                int NB, const int* __restrict__ blkCount,
                                                int* __restrict__ e2p) {
    __shared__ int cur[MAXNB];
    int tid = threadIdx.x;
    int blk = blockIdx.x;
    for (int b = tid; b < NB; b += 256) cur[b] = blkCount[b * NBLK + blk];
    __syncthreads();
    int ch = (E + NBLK - 1) / NBLK;
    int beg = blk * ch, end = min(beg + ch, E);
    for (int i = beg + tid; i < end; i += 256) {
        int s = src[i], t = dst[i];
        int pos = atomicAdd(&cur[t >> 8], 1);
        e2p[pos] = (s << 8) | (t & 255);
    }
}

// ---- fused CSR finalize: per-bucket histogram+scan -> rowptr & dinv, scatter srcs ----
__global__ __launch_bounds__(256) void k_csrdeg(const int* __restrict__ e2p,
                                                const int* __restrict__ bucketBase,
                                                int N, int E,
                                                int* __restrict__ rowptr,
                                                float* __restrict__ dinv,
                                                int* __restrict__ srcs) {
    __shared__ int cnt[256];
    __shared__ int sd[256];
    __shared__ int cur[256];
    int tid = threadIdx.x;
    int node0 = blockIdx.x << 8;
    int bb = bucketBase[blockIdx.x];
    int end = bucketBase[blockIdx.x + 1];
    cnt[tid] = 0;
    __syncthreads();
    for (int i = bb + tid; i < end; i += 256) atomicAdd(&cnt[e2p[i] & 255], 1);
    __syncthreads();
    sd[tid] = cnt[tid];
    __syncthreads();
    for (int off = 1; off < 256; off <<= 1) {
        int tmp = (tid >= off) ? sd[tid - off] : 0;
        __syncthreads();
        sd[tid] += tmp;
        __syncthreads();
    }
    int excl = (tid == 0) ? 0 : sd[tid - 1];
    int node = node0 + tid;
    if (node < N) {
        rowptr[node] = bb + excl;
        dinv[node] = rsqrtf((float)(cnt[tid] + 1));
    }
    cur[tid] = bb + excl;
    if (blockIdx.x == 0 && tid == 0) rowptr[N] = E;
    __syncthreads();
    for (int i = bb + tid; i < end; i += 256) {
        int p = e2p[i];
        int pos = atomicAdd(&cur[p & 255], 1);
        srcs[pos] = p >> 8;
    }
}

// ---- fused gather + relu + mean-pool ----
// Block: 16 groups x 16 lanes, TILES tiles of 16 nodes (64 nodes/block).
// Per tile: per-group gather (identical to k_gather, 4-deep MLP) -> fp32 row to
// LDS (non-atomic) -> sync -> threads 0..63 run-accumulate over 16 rows with
// sorted-batch boundary flush. ~110k flush atomics total (same as old k_pool).
__global__ __launch_bounds__(256) void k_gpool(
    const ushort4* __restrict__ hs4, const float* __restrict__ dinv,
    const int* __restrict__ rowptr, const int* __restrict__ srcs,
    const int* __restrict__ batch, const float* __restrict__ b1, int N,
    float* __restrict__ gsum, float* __restrict__ gcnt) {
    __shared__ float lds[16 * 68];
    __shared__ int bt[16];
    int tid = threadIdx.x;
    int g16 = tid >> 4;
    int c4 = tid & 15;
    float4 b = ((const float4*)b1)[c4];
    int ch = tid;          // channel for reduce phase (threads 0..63)
    float psum = 0.f;
    float pcnt = 0.f;
    int cur_g = -1;
    int base0 = blockIdx.x * (16 * TILES);
    for (int t = 0; t < TILES; ++t) {
        int node = base0 + t * 16 + g16;
        float4 rv = make_float4(0.f, 0.f, 0.f, 0.f);
        if (node < N) {
            int begin = rowptr[node];
            int end = rowptr[node + 1];
            ushort4 u = hs4[(size_t)node * 16 + c4];  // self-loop (already *dinv)
            float4 sum = make_float4(bf2f(u.x), bf2f(u.y), bf2f(u.z), bf2f(u.w));
            int k = begin;
            for (; k + 3 < end; k += 4) {  // four independent gathers in flight
                int s0 = srcs[k];
                int s1 = srcs[k + 1];
                int s2 = srcs[k + 2];
                int s3 = srcs[k + 3];
                ushort4 u0 = hs4[(size_t)s0 * 16 + c4];
                ushort4 u1 = hs4[(size_t)s1 * 16 + c4];
                ushort4 u2 = hs4[(size_t)s2 * 16 + c4];
                ushort4 u3 = hs4[(size_t)s3 * 16 + c4];
                sum.x += (bf2f(u0.x) + bf2f(u1.x)) + (bf2f(u2.x) + bf2f(u3.x));
                sum.y += (bf2f(u0.y) + bf2f(u1.y)) + (bf2f(u2.y) + bf2f(u3.y));
                sum.z += (bf2f(u0.z) + bf2f(u1.z)) + (bf2f(u2.z) + bf2f(u3.z));
                sum.w += (bf2f(u0.w) + bf2f(u1.w)) + (bf2f(u2.w) + bf2f(u3.w));
            }
            for (; k < end; ++k) {
                int s = srcs[k];
                ushort4 uu = hs4[(size_t)s * 16 + c4];
                sum.x += bf2f(uu.x); sum.y += bf2f(uu.y);
                sum.z += bf2f(uu.z); sum.w += bf2f(uu.w);
            }
            float d = dinv[node];
            rv.x = fmaxf(sum.x * d + b.x, 0.f);
            rv.y = fmaxf(sum.y * d + b.y, 0.f);
            rv.z = fmaxf(sum.z * d + b.z, 0.f);
            rv.w = fmaxf(sum.w * d + b.w, 0.f);
        }
        float* row = &lds[g16 * 68 + c4 * 4];
        row[0] = rv.x; row[1] = rv.y; row[2] = rv.z; row[3] = rv.w;
        if (c4 == 0) bt[g16] = (node < N) ? batch[node] : -1;
        __syncthreads();
        if (tid < 64) {
            for (int g = 0; g < 16; ++g) {
                int bg = bt[g];
                if (bg < 0) break;  // tail (invalid nodes only at the end)
                if (bg != cur_g) {
                    if (cur_g >= 0) {
                        atomicAdd(&gsum[cur_g * D + ch], psum);
                        if (ch == 0) atomicAdd(&gcnt[cur_g], pcnt);
                    }
                    psum = 0.f; pcnt = 0.f; cur_g = bg;
                }
                psum += lds[g * 68 + ch];
                pcnt += 1.f;
            }
        }
        __syncthreads();
    }
    if (tid < 64 && cur_g >= 0) {
        atomicAdd(&gsum[cur_g * D + ch], psum);
        if (ch == 0) atomicAdd(&gcnt[cur_g], pcnt);
    }
}

// ---- head ----
__global__ void k_head(const float* __restrict__ gsum, const float* __restrict__ gcnt,
                       const float* __restrict__ W2, const float* __restrict__ b2,
                       float* __restrict__ out) {
    int g = threadIdx.x;
    if (g >= NG) return;
    float cnt = gcnt[g];
    cnt = cnt > 1.f ? cnt : 1.f;
    float inv = 1.f / cnt;
    float logits[NCLS];
#pragma unroll
    for (int c = 0; c < NCLS; ++c) logits[c] = b2[c];
    for (int k = 0; k < D; ++k) {
        float hk = gsum[g * D + k] * inv;
#pragma unroll
        for (int c = 0; c < NCLS; ++c) logits[c] += hk * W2[k * NCLS + c];
    }
    float m = logits[0];
#pragma unroll
    for (int c = 1; c < NCLS; ++c) m = fmaxf(m, logits[c]);
    float se = 0.f;
#pragma unroll
    for (int c = 0; c < NCLS; ++c) se += expf(logits[c] - m);
    float lse = m + logf(se);
#pragma unroll
    for (int c = 0; c < NCLS; ++c) out[g * NCLS + c] = logits[c] - lse;
}

static inline size_t pad256(size_t x) { return (x + 255) & ~(size_t)255; }

extern "C" void kernel_launch(void* const* d_in, const int* in_sizes, int n_in,
                              void* d_out, int out_size, void* d_ws, size_t ws_size,
                              hipStream_t stream) {
    const float* x     = (const float*)d_in[0];
    const int*   ei    = (const int*)d_in[1];   // [2, E]: src row then dst row
    const int*   batch = (const int*)d_in[2];
    const float* W1    = (const float*)d_in[3];
    const float* b1    = (const float*)d_in[4];
    const float* W2    = (const float*)d_in[5];
    const float* b2    = (const float*)d_in[6];
    float* out = (float*)d_out;

    const int N = in_sizes[0] / D;   // 100000
    const int E = in_sizes[1] / 2;   // 1000000
    const int NB = (N + 255) >> 8;   // 391 coarse buckets

    char* w = (char*)d_ws;
    ushort4* hs4      = (ushort4*)w; w += pad256((size_t)N * D * 2);
    float* dinv       = (float*)w;  w += pad256((size_t)N * 4);
    int*   rowptr     = (int*)w;    w += pad256((size_t)(N + 1) * 4);
    int*   srcs       = (int*)w;    w += pad256((size_t)E * 4);
    int*   e2p        = (int*)w;    w += pad256((size_t)E * 4);
    int*   blkCount   = (int*)w;    w += pad256((size_t)MAXNB * NBLK * 4);
    int*   bucketBase = (int*)w;    w += pad256((size_t)(MAXNB + 1) * 4);
    float* gsum       = (float*)w;  w += pad256((size_t)NG * D * 4);
    float* gcnt       = (float*)w;  w += pad256((size_t)NG * 4);

    const int* e_src = ei;
    const int* e_dst = ei + E;

    k_bcount<<<NBLK, 256, 0, stream>>>(e_dst, E, NB, blkCount, gsum, gcnt);
    k_bbase<<<1, 512, 0, stream>>>(blkCount, NB, E, bucketBase);
    k_bplace<<<NBLK, 256, 0, stream>>>(e_src, e_dst, E, NB, blkCount, e2p);
    k_csrdeg<<<NB, 256, 0, stream>>>(e2p, bucketBase, N, E, rowptr, dinv, srcs);

    k_xw1<<<(N + 63) / 64, 256, 0, stream>>>(x, W1, dinv, N, hs4);

    {
        int blocks = (N + 16 * TILES - 1) / (16 * TILES);
        k_gpool<<<blocks, 256, 0, stream>>>(hs4, dinv, rowptr, srcs, batch, b1,
                                            N, gsum, gcnt);
    }
    k_head<<<1, 128, 0, stream>>>(gsum, gcnt, W2, b2, out);
}

// Round 15
// 109.261 us; speedup vs baseline: 4.6545x; 1.0554x over previous
//
#include <hip/hip_runtime.h>

#define D 64
#define NCLS 10
#define NG 128
#define NBLK 128  // partition blocks for bucket build
#define MAXNB 512 // max coarse buckets (N/256)
#define TILES 2   // 32-node tiles per k_gpool block (64 nodes/block)

// bf16 helpers (RNE encode, cheap decode)
__device__ __forceinline__ unsigned short f2bf(float v) {
    unsigned b = __float_as_uint(v);
    b += 0x7fff + ((b >> 16) & 1);
    return (unsigned short)(b >> 16);
}
__device__ __forceinline__ float bf2f(unsigned short h) {
    return __uint_as_float(((unsigned)h) << 16);
}
// unpack 2 packed bf16 (lo|hi<<16) and add into two floats
__device__ __forceinline__ void upadd(unsigned v, float& lo, float& hi) {
    lo += __uint_as_float(v << 16);
    hi += __uint_as_float(v & 0xffff0000u);
}

// ---- h_scaled = (x @ W1) * dinv(row) -> bf16, LDS-tiled register-blocked GEMM ----
__global__ __launch_bounds__(256) void k_xw1(const float* __restrict__ x,
                      const float* __restrict__ W1, const float* __restrict__ dinv,
                      int N, ushort4* __restrict__ hs4) {
    __shared__ float wl[D * D];   // W1[k][c]
    __shared__ float xt[64 * D];  // x-tile, row-major [r][k]
    int tid = threadIdx.x;
    const float4* W4 = (const float4*)W1;
    float4* wl4 = (float4*)wl;
#pragma unroll
    for (int i = 0; i < 4; ++i) wl4[i * 256 + tid] = W4[i * 256 + tid];
    int row0 = blockIdx.x * 64;
    const float4* x4 = (const float4*)x;
    float4* xt4 = (float4*)xt;
#pragma unroll
    for (int i = 0; i < 4; ++i) {
        int flat = i * 256 + tid;
        int row = row0 + (flat >> 4);
        float4 v = make_float4(0.f, 0.f, 0.f, 0.f);
        if (row < N) v = x4[(size_t)row * 16 + (flat & 15)];
        xt4[flat] = v;
    }
    __syncthreads();
    int col4 = tid & 15;
    int rowg = tid >> 4;
    float4 acc[4];
#pragma unroll
    for (int i = 0; i < 4; ++i) acc[i] = make_float4(0.f, 0.f, 0.f, 0.f);
#pragma unroll 8
    for (int k = 0; k < D; ++k) {
        float4 wv = *(const float4*)&wl[k * D + col4 * 4];
#pragma unroll
        for (int i = 0; i < 4; ++i) {
            float xv = xt[(rowg * 4 + i) * D + k];
            acc[i].x += xv * wv.x;
            acc[i].y += xv * wv.y;
            acc[i].z += xv * wv.z;
            acc[i].w += xv * wv.w;
        }
    }
#pragma unroll
    for (int i = 0; i < 4; ++i) {
        int row = row0 + rowg * 4 + i;
        if (row >= N) continue;
        float d = dinv[row];
        ushort4 o;
        o.x = f2bf(acc[i].x * d);
        o.y = f2bf(acc[i].y * d);
        o.z = f2bf(acc[i].z * d);
        o.w = f2bf(acc[i].w * d);
        hs4[(size_t)row * 16 + col4] = o;
    }
}

// ---- bucket build pass 1: per-block histogram of dst>>8 (+ zero gsum/gcnt) ----
__global__ __launch_bounds__(256) void k_bcount(const int* __restrict__ dst, int E,
                                                int NB, int* __restrict__ blkCount,
                                                float* __restrict__ gsum,
                                                float* __restrict__ gcnt) {
    __shared__ int cnt[MAXNB];
    int tid = threadIdx.x;
    int blk = blockIdx.x;
    int gt = blk * 256 + tid;
    if (gt < NG * D) gsum[gt] = 0.f;
    if (gt < NG) gcnt[gt] = 0.f;
    for (int b = tid; b < NB; b += 256) cnt[b] = 0;
    __syncthreads();
    int ch = (E + NBLK - 1) / NBLK;
    int beg = blk * ch, end = min(beg + ch, E);
    for (int i = beg + tid; i < end; i += 256) atomicAdd(&cnt[dst[i] >> 8], 1);
    __syncthreads();
    for (int b = tid; b < NB; b += 256) blkCount[b * NBLK + blk] = cnt[b];
}

// ---- bucket build pass 2: totals -> exclusive bases, per-(bucket,block) bases ----
__global__ __launch_bounds__(512) void k_bbase(int* __restrict__ blkCount, int NB, int E,
                                               int* __restrict__ bucketBase) {
    __shared__ int sd[512];
    int tid = threadIdx.x;
    int4 c[NBLK / 4];
    int tot = 0;
    if (tid < NB) {
        const int4* p = (const int4*)&blkCount[tid * NBLK];
#pragma unroll
        for (int j = 0; j < NBLK / 4; ++j) {
            c[j] = p[j];
            tot += c[j].x + c[j].y + c[j].z + c[j].w;
        }
    }
    sd[tid] = (tid < NB) ? tot : 0;
    __syncthreads();
    for (int off = 1; off < 512; off <<= 1) {
        int tmp = (tid >= off) ? sd[tid - off] : 0;
        __syncthreads();
        sd[tid] += tmp;
        __syncthreads();
    }
    if (tid < NB) {
        int run = (tid == 0) ? 0 : sd[tid - 1];
        bucketBase[tid] = run;
        int4* p = (int4*)&blkCount[tid * NBLK];
#pragma unroll
        for (int j = 0; j < NBLK / 4; ++j) {
            int t0 = c[j].x; c[j].x = run; run += t0;
            int t1 = c[j].y; c[j].y = run; run += t1;
            int t2 = c[j].z; c[j].z = run; run += t2;
            int t3 = c[j].w; c[j].w = run; run += t3;
            p[j] = c[j];
        }
    }
    if (tid == 0) bucketBase[NB] = E;
}

// ---- bucket build pass 3: place packed (src<<8)|dstLocal grouped by bucket ----
__global__ __launch_bounds__(256) void k_bplace(const int* __restrict__ src,
                                                const int* __restrict__ dst, int E,
                                                int NB, const int* __restrict__ blkCount,
                                                int* __restrict__ e2p) {
    __shared__ int cur[MAXNB];
    int tid = threadIdx.x;
    int blk = blockIdx.x;
    for (int b = tid; b < NB; b += 256) cur[b] = blkCount[b * NBLK + blk];
    __syncthreads();
    int ch = (E + NBLK - 1) / NBLK;
    int beg = blk * ch, end = min(beg + ch, E);
    for (int i = beg + tid; i < end; i += 256) {
        int s = src[i], t = dst[i];
        int pos = atomicAdd(&cur[t >> 8], 1);
        e2p[pos] = (s << 8) | (t & 255);
    }
}

// ---- fused CSR finalize: per-bucket histogram+scan -> rowptr & dinv, scatter srcs ----
__global__ __launch_bounds__(256) void k_csrdeg(const int* __restrict__ e2p,
                                                const int* __restrict__ bucketBase,
                                                int N, int E,
                                                int* __restrict__ rowptr,
                                                float* __restrict__ dinv,
                                                int* __restrict__ srcs) {
    __shared__ int cnt[256];
    __shared__ int sd[256];
    __shared__ int cur[256];
    int tid = threadIdx.x;
    int node0 = blockIdx.x << 8;
    int bb = bucketBase[blockIdx.x];
    int end = bucketBase[blockIdx.x + 1];
    cnt[tid] = 0;
    __syncthreads();
    for (int i = bb + tid; i < end; i += 256) atomicAdd(&cnt[e2p[i] & 255], 1);
    __syncthreads();
    sd[tid] = cnt[tid];
    __syncthreads();
    for (int off = 1; off < 256; off <<= 1) {
        int tmp = (tid >= off) ? sd[tid - off] : 0;
        __syncthreads();
        sd[tid] += tmp;
        __syncthreads();
    }
    int excl = (tid == 0) ? 0 : sd[tid - 1];
    int node = node0 + tid;
    if (node < N) {
        rowptr[node] = bb + excl;
        dinv[node] = rsqrtf((float)(cnt[tid] + 1));
    }
    cur[tid] = bb + excl;
    if (blockIdx.x == 0 && tid == 0) rowptr[N] = E;
    __syncthreads();
    for (int i = bb + tid; i < end; i += 256) {
        int p = e2p[i];
        int pos = atomicAdd(&cur[p & 255], 1);
        srcs[pos] = p >> 8;
    }
}

// ---- fused gather + relu + mean-pool, 8-lane groups (16B/lane loads) ----
// Block: 32 groups x 8 lanes, TILES tiles of 32 nodes (64 nodes/block). Per tile:
// per-group gather (4-deep MLP, uint4 loads = 8 bf16 channels/lane) -> fp32 row
// to LDS -> sync -> threads 0..63 run-accumulate over 32 rows with sorted-batch
// boundary flush (~110k flush atomics total).
__global__ __launch_bounds__(256) void k_gpool(
    const uint4* __restrict__ hsv, const float* __restrict__ dinv,
    const int* __restrict__ rowptr, const int* __restrict__ srcs,
    const int* __restrict__ batch, const float* __restrict__ b1, int N,
    float* __restrict__ gsum, float* __restrict__ gcnt) {
    __shared__ float lds[32 * 68];
    __shared__ int bt[32];
    int tid = threadIdx.x;
    int g32 = tid >> 3;     // group (node slot 0..31)
    int c8 = tid & 7;       // channel octet: channels c8*8 .. c8*8+7
    float4 blo = ((const float4*)b1)[c8 * 2];
    float4 bhi = ((const float4*)b1)[c8 * 2 + 1];
    int ch = tid;           // channel for reduce phase (threads 0..63)
    float psum = 0.f;
    float pcnt = 0.f;
    int cur_g = -1;
    int base0 = blockIdx.x * (32 * TILES);
    for (int t = 0; t < TILES; ++t) {
        int node = base0 + t * 32 + g32;
        float4 alo = make_float4(0.f, 0.f, 0.f, 0.f);
        float4 ahi = make_float4(0.f, 0.f, 0.f, 0.f);
        if (node < N) {
            int begin = rowptr[node];
            int end = rowptr[node + 1];
            {   // self-loop (already *dinv[node])
                uint4 v = hsv[(size_t)node * 8 + c8];
                upadd(v.x, alo.x, alo.y); upadd(v.y, alo.z, alo.w);
                upadd(v.z, ahi.x, ahi.y); upadd(v.w, ahi.z, ahi.w);
            }
            int k = begin;
            for (; k + 3 < end; k += 4) {  // four independent gathers in flight
                int s0 = srcs[k];
                int s1 = srcs[k + 1];
                int s2 = srcs[k + 2];
                int s3 = srcs[k + 3];
                uint4 v0 = hsv[(size_t)s0 * 8 + c8];
                uint4 v1 = hsv[(size_t)s1 * 8 + c8];
                uint4 v2 = hsv[(size_t)s2 * 8 + c8];
                uint4 v3 = hsv[(size_t)s3 * 8 + c8];
                upadd(v0.x, alo.x, alo.y); upadd(v0.y, alo.z, alo.w);
                upadd(v0.z, ahi.x, ahi.y); upadd(v0.w, ahi.z, ahi.w);
                upadd(v1.x, alo.x, alo.y); upadd(v1.y, alo.z, alo.w);
                upadd(v1.z, ahi.x, ahi.y); upadd(v1.w, ahi.z, ahi.w);
                upadd(v2.x, alo.x, alo.y); upadd(v2.y, alo.z, alo.w);
                upadd(v2.z, ahi.x, ahi.y); upadd(v2.w, ahi.z, ahi.w);
                upadd(v3.x, alo.x, alo.y); upadd(v3.y, alo.z, alo.w);
                upadd(v3.z, ahi.x, ahi.y); upadd(v3.w, ahi.z, ahi.w);
            }
            for (; k < end; ++k) {
                int s = srcs[k];
                uint4 v = hsv[(size_t)s * 8 + c8];
                upadd(v.x, alo.x, alo.y); upadd(v.y, alo.z, alo.w);
                upadd(v.z, ahi.x, ahi.y); upadd(v.w, ahi.z, ahi.w);
            }
            float d = dinv[node];
            alo.x = fmaxf(alo.x * d + blo.x, 0.f);
            alo.y = fmaxf(alo.y * d + blo.y, 0.f);
            alo.z = fmaxf(alo.z * d + blo.z, 0.f);
            alo.w = fmaxf(alo.w * d + blo.w, 0.f);
            ahi.x = fmaxf(ahi.x * d + bhi.x, 0.f);
            ahi.y = fmaxf(ahi.y * d + bhi.y, 0.f);
            ahi.z = fmaxf(ahi.z * d + bhi.z, 0.f);
            ahi.w = fmaxf(ahi.w * d + bhi.w, 0.f);
        }
        float* row = &lds[g32 * 68 + c8 * 8];
        row[0] = alo.x; row[1] = alo.y; row[2] = alo.z; row[3] = alo.w;
        row[4] = ahi.x; row[5] = ahi.y; row[6] = ahi.z; row[7] = ahi.w;
        if (c8 == 0) bt[g32] = (node < N) ? batch[node] : -1;
        __syncthreads();
        if (tid < 64) {
            for (int g = 0; g < 32; ++g) {
                int bg = bt[g];
                if (bg < 0) break;  // tail (invalid nodes only at the end)
                if (bg != cur_g) {
                    if (cur_g >= 0) {
                        atomicAdd(&gsum[cur_g * D + ch], psum);
                        if (ch == 0) atomicAdd(&gcnt[cur_g], pcnt);
                    }
                    psum = 0.f; pcnt = 0.f; cur_g = bg;
                }
                psum += lds[g * 68 + ch];
                pcnt += 1.f;
            }
        }
        __syncthreads();
    }
    if (tid < 64 && cur_g >= 0) {
        atomicAdd(&gsum[cur_g * D + ch], psum);
        if (ch == 0) atomicAdd(&gcnt[cur_g], pcnt);
    }
}

// ---- head ----
__global__ void k_head(const float* __restrict__ gsum, const float* __restrict__ gcnt,
                       const float* __restrict__ W2, const float* __restrict__ b2,
                       float* __restrict__ out) {
    int g = threadIdx.x;
    if (g >= NG) return;
    float cnt = gcnt[g];
    cnt = cnt > 1.f ? cnt : 1.f;
    float inv = 1.f / cnt;
    float logits[NCLS];
#pragma unroll
    for (int c = 0; c < NCLS; ++c) logits[c] = b2[c];
    for (int k = 0; k < D; ++k) {
        float hk = gsum[g * D + k] * inv;
#pragma unroll
        for (int c = 0; c < NCLS; ++c) logits[c] += hk * W2[k * NCLS + c];
    }
    float m = logits[0];
#pragma unroll
    for (int c = 1; c < NCLS; ++c) m = fmaxf(m, logits[c]);
    float se = 0.f;
#pragma unroll
    for (int c = 0; c < NCLS; ++c) se += expf(logits[c] - m);
    float lse = m + logf(se);
#pragma unroll
    for (int c = 0; c < NCLS; ++c) out[g * NCLS + c] = logits[c] - lse;
}

static inline size_t pad256(size_t x) { return (x + 255) & ~(size_t)255; }

extern "C" void kernel_launch(void* const* d_in, const int* in_sizes, int n_in,
                              void* d_out, int out_size, void* d_ws, size_t ws_size,
                              hipStream_t stream) {
    const float* x     = (const float*)d_in[0];
    const int*   ei    = (const int*)d_in[1];   // [2, E]: src row then dst row
    const int*   batch = (const int*)d_in[2];
    const float* W1    = (const float*)d_in[3];
    const float* b1    = (const float*)d_in[4];
    const float* W2    = (const float*)d_in[5];
    const float* b2    = (const float*)d_in[6];
    float* out = (float*)d_out;

    const int N = in_sizes[0] / D;   // 100000
    const int E = in_sizes[1] / 2;   // 1000000
    const int NB = (N + 255) >> 8;   // 391 coarse buckets

    char* w = (char*)d_ws;
    ushort4* hs4      = (ushort4*)w; w += pad256((size_t)N * D * 2);
    float* dinv       = (float*)w;  w += pad256((size_t)N * 4);
    int*   rowptr     = (int*)w;    w += pad256((size_t)(N + 1) * 4);
    int*   srcs       = (int*)w;    w += pad256((size_t)E * 4);
    int*   e2p        = (int*)w;    w += pad256((size_t)E * 4);
    int*   blkCount   = (int*)w;    w += pad256((size_t)MAXNB * NBLK * 4);
    int*   bucketBase = (int*)w;    w += pad256((size_t)(MAXNB + 1) * 4);
    float* gsum       = (float*)w;  w += pad256((size_t)NG * D * 4);
    float* gcnt      = (float*)w;   w += pad256((size_t)NG * 4);

    const int* e_src = ei;
    const int* e_dst = ei + E;

    k_bcount<<<NBLK, 256, 0, stream>>>(e_dst, E, NB, blkCount, gsum, gcnt);
    k_bbase<<<1, 512, 0, stream>>>(blkCount, NB, E, bucketBase);
    k_bplace<<<NBLK, 256, 0, stream>>>(e_src, e_dst, E, NB, blkCount, e2p);
    k_csrdeg<<<NB, 256, 0, stream>>>(e2p, bucketBase, N, E, rowptr, dinv, srcs);

    k_xw1<<<(N + 63) / 64, 256, 0, stream>>>(x, W1, dinv, N, hs4);

    {
        int blocks = (N + 32 * TILES - 1) / (32 * TILES);
        k_gpool<<<blocks, 256, 0, stream>>>((const uint4*)hs4, dinv, rowptr, srcs,
                                            batch, b1, N, gsum, gcnt);
    }
    k_head<<<1, 128, 0, stream>>>(gsum, gcnt, W2, b2, out);
}

// Round 16
// 108.688 us; speedup vs baseline: 4.6790x; 1.0053x over previous
//
#include <hip/hip_runtime.h>

#define D 64
#define NCLS 10
#define NG 128
#define NBLK 128  // partition blocks for bucket build
#define MAXNB 512 // max coarse buckets (N/256)
#define TILES 2   // 32-node tiles per k_gpool block (64 nodes/block)
#define RSH 14    // src-range shift: ranges of 16384 rows (2 MB of table)
#define NR 8      // range slots per node (99999>>14 = 6, 8 for alignment)

// bf16 helpers (RNE encode, cheap decode)
__device__ __forceinline__ unsigned short f2bf(float v) {
    unsigned b = __float_as_uint(v);
    b += 0x7fff + ((b >> 16) & 1);
    return (unsigned short)(b >> 16);
}
__device__ __forceinline__ float bf2f(unsigned short h) {
    return __uint_as_float(((unsigned)h) << 16);
}
// unpack 2 packed bf16 (lo|hi<<16) and add into two floats
__device__ __forceinline__ void upadd(unsigned v, float& lo, float& hi) {
    lo += __uint_as_float(v << 16);
    hi += __uint_as_float(v & 0xffff0000u);
}

// ---- h_scaled = (x @ W1) * dinv(row) -> bf16, LDS-tiled register-blocked GEMM ----
__global__ __launch_bounds__(256) void k_xw1(const float* __restrict__ x,
                      const float* __restrict__ W1, const float* __restrict__ dinv,
                      int N, ushort4* __restrict__ hs4) {
    __shared__ float wl[D * D];   // W1[k][c]
    __shared__ float xt[64 * D];  // x-tile, row-major [r][k]
    int tid = threadIdx.x;
    const float4* W4 = (const float4*)W1;
    float4* wl4 = (float4*)wl;
#pragma unroll
    for (int i = 0; i < 4; ++i) wl4[i * 256 + tid] = W4[i * 256 + tid];
    int row0 = blockIdx.x * 64;
    const float4* x4 = (const float4*)x;
    float4* xt4 = (float4*)xt;
#pragma unroll
    for (int i = 0; i < 4; ++i) {
        int flat = i * 256 + tid;
        int row = row0 + (flat >> 4);
        float4 v = make_float4(0.f, 0.f, 0.f, 0.f);
        if (row < N) v = x4[(size_t)row * 16 + (flat & 15)];
        xt4[flat] = v;
    }
    __syncthreads();
    int col4 = tid & 15;
    int rowg = tid >> 4;
    float4 acc[4];
#pragma unroll
    for (int i = 0; i < 4; ++i) acc[i] = make_float4(0.f, 0.f, 0.f, 0.f);
#pragma unroll 8
    for (int k = 0; k < D; ++k) {
        float4 wv = *(const float4*)&wl[k * D + col4 * 4];
#pragma unroll
        for (int i = 0; i < 4; ++i) {
            float xv = xt[(rowg * 4 + i) * D + k];
            acc[i].x += xv * wv.x;
            acc[i].y += xv * wv.y;
            acc[i].z += xv * wv.z;
            acc[i].w += xv * wv.w;
        }
    }
#pragma unroll
    for (int i = 0; i < 4; ++i) {
        int row = row0 + rowg * 4 + i;
        if (row >= N) continue;
        float d = dinv[row];
        ushort4 o;
        o.x = f2bf(acc[i].x * d);
        o.y = f2bf(acc[i].y * d);
        o.z = f2bf(acc[i].z * d);
        o.w = f2bf(acc[i].w * d);
        hs4[(size_t)row * 16 + col4] = o;
    }
}

// ---- bucket build pass 1: per-block histogram of dst>>8 (+ zero gsum/gcnt) ----
__global__ __launch_bounds__(256) void k_bcount(const int* __restrict__ dst, int E,
                                                int NB, int* __restrict__ blkCount,
                                                float* __restrict__ gsum,
                                                float* __restrict__ gcnt) {
    __shared__ int cnt[MAXNB];
    int tid = threadIdx.x;
    int blk = blockIdx.x;
    int gt = blk * 256 + tid;
    if (gt < NG * D) gsum[gt] = 0.f;
    if (gt < NG) gcnt[gt] = 0.f;
    for (int b = tid; b < NB; b += 256) cnt[b] = 0;
    __syncthreads();
    int ch = (E + NBLK - 1) / NBLK;
    int beg = blk * ch, end = min(beg + ch, E);
    for (int i = beg + tid; i < end; i += 256) atomicAdd(&cnt[dst[i] >> 8], 1);
    __syncthreads();
    for (int b = tid; b < NB; b += 256) blkCount[b * NBLK + blk] = cnt[b];
}

// ---- bucket build pass 2: totals -> exclusive bases, per-(bucket,block) bases ----
__global__ __launch_bounds__(512) void k_bbase(int* __restrict__ blkCount, int NB, int E,
                                               int* __restrict__ bucketBase) {
    __shared__ int sd[512];
    int tid = threadIdx.x;
    int4 c[NBLK / 4];
    int tot = 0;
    if (tid < NB) {
        const int4* p = (const int4*)&blkCount[tid * NBLK];
#pragma unroll
        for (int j = 0; j < NBLK / 4; ++j) {
            c[j] = p[j];
            tot += c[j].x + c[j].y + c[j].z + c[j].w;
        }
    }
    sd[tid] = (tid < NB) ? tot : 0;
    __syncthreads();
    for (int off = 1; off < 512; off <<= 1) {
        int tmp = (tid >= off) ? sd[tid - off] : 0;
        __syncthreads();
        sd[tid] += tmp;
        __syncthreads();
    }
    if (tid < NB) {
        int run = (tid == 0) ? 0 : sd[tid - 1];
        bucketBase[tid] = run;
        int4* p = (int4*)&blkCount[tid * NBLK];
#pragma unroll
        for (int j = 0; j < NBLK / 4; ++j) {
            int t0 = c[j].x; c[j].x = run; run += t0;
            int t1 = c[j].y; c[j].y = run; run += t1;
            int t2 = c[j].z; c[j].z = run; run += t2;
            int t3 = c[j].w; c[j].w = run; run += t3;
            p[j] = c[j];
        }
    }
    if (tid == 0) bucketBase[NB] = E;
}

// ---- bucket build pass 3: place packed (src<<8)|dstLocal grouped by bucket ----
__global__ __launch_bounds__(256) void k_bplace(const int* __restrict__ src,
                                                const int* __restrict__ dst, int E,
                                                int NB, const int* __restrict__ blkCount,
                                                int* __restrict__ e2p) {
    __shared__ int cur[MAXNB];
    int tid = threadIdx.x;
    int blk = blockIdx.x;
    for (int b = tid; b < NB; b += 256) cur[b] = blkCount[b * NBLK + blk];
    __syncthreads();
    int ch = (E + NBLK - 1) / NBLK;
    int beg = blk * ch, end = min(beg + ch, E);
    for (int i = beg + tid; i < end; i += 256) {
        int s = src[i], t = dst[i];
        int pos = atomicAdd(&cur[t >> 8], 1);
        e2p[pos] = (s << 8) | (t & 255);
    }
}

// ---- fused CSR finalize: per-(node,src-range) histogram+scan -> rowptr & dinv,
// scatter srcs grouped by (dstLocal, src>>RSH). Each node's edge list ends up
// src-range-sorted, which phase-aligns k_gpool's table accesses (L2 locality).
// Any intra-node order is a valid sum order -> correctness-neutral reorder.
__global__ __launch_bounds__(256) void k_csrdeg(const int* __restrict__ e2p,
                                                const int* __restrict__ bucketBase,
                                                int N, int E,
                                                int* __restrict__ rowptr,
                                                float* __restrict__ dinv,
                                                int* __restrict__ srcs) {
    __shared__ int cnt[256 * NR];
    __shared__ int cur[256 * NR];
    __shared__ int sd[256];
    int tid = threadIdx.x;
    int node0 = blockIdx.x << 8;
    int bb = bucketBase[blockIdx.x];
    int end = bucketBase[blockIdx.x + 1];
    for (int b = tid; b < 256 * NR; b += 256) cnt[b] = 0;
    __syncthreads();
    for (int i = bb + tid; i < end; i += 256) {
        int p = e2p[i];
        int key = ((p & 255) << 3) | min((p >> 8) >> RSH, NR - 1);
        atomicAdd(&cnt[key], 1);
    }
    __syncthreads();
    // thread tid = node-local id: its NR range slots are cnt[tid*NR .. +NR)
    int c[NR];
    int tot = 0;
#pragma unroll
    for (int r = 0; r < NR; ++r) { c[r] = cnt[tid * NR + r]; tot += c[r]; }
    sd[tid] = tot;
    __syncthreads();
    for (int off = 1; off < 256; off <<= 1) {
        int tmp = (tid >= off) ? sd[tid - off] : 0;
        __syncthreads();
        sd[tid] += tmp;
        __syncthreads();
    }
    int excl = (tid == 0) ? 0 : sd[tid - 1];
    int node = node0 + tid;
    if (node < N) {
        rowptr[node] = bb + excl;
        dinv[node] = rsqrtf((float)(tot + 1));
    }
    {
        int run = bb + excl;
#pragma unroll
        for (int r = 0; r < NR; ++r) { cur[tid * NR + r] = run; run += c[r]; }
    }
    if (blockIdx.x == 0 && tid == 0) rowptr[N] = E;
    __syncthreads();
    for (int i = bb + tid; i < end; i += 256) {
        int p = e2p[i];
        int s = p >> 8;
        int key = ((p & 255) << 3) | min(s >> RSH, NR - 1);
        int pos = atomicAdd(&cur[key], 1);
        srcs[pos] = s;
    }
}

// ---- fused gather + relu + mean-pool, 8-lane groups (16B/lane loads) ----
__global__ __launch_bounds__(256) void k_gpool(
    const uint4* __restrict__ hsv, const float* __restrict__ dinv,
    const int* __restrict__ rowptr, const int* __restrict__ srcs,
    const int* __restrict__ batch, const float* __restrict__ b1, int N,
    float* __restrict__ gsum, float* __restrict__ gcnt) {
    __shared__ float lds[32 * 68];
    __shared__ int bt[32];
    int tid = threadIdx.x;
    int g32 = tid >> 3;     // group (node slot 0..31)
    int c8 = tid & 7;       // channel octet: channels c8*8 .. c8*8+7
    float4 blo = ((const float4*)b1)[c8 * 2];
    float4 bhi = ((const float4*)b1)[c8 * 2 + 1];
    int ch = tid;           // channel for reduce phase (threads 0..63)
    float psum = 0.f;
    float pcnt = 0.f;
    int cur_g = -1;
    int base0 = blockIdx.x * (32 * TILES);
    for (int t = 0; t < TILES; ++t) {
        int node = base0 + t * 32 + g32;
        float4 alo = make_float4(0.f, 0.f, 0.f, 0.f);
        float4 ahi = make_float4(0.f, 0.f, 0.f, 0.f);
        if (node < N) {
            int begin = rowptr[node];
            int end = rowptr[node + 1];
            {   // self-loop (already *dinv[node])
                uint4 v = hsv[(size_t)node * 8 + c8];
                upadd(v.x, alo.x, alo.y); upadd(v.y, alo.z, alo.w);
                upadd(v.z, ahi.x, ahi.y); upadd(v.w, ahi.z, ahi.w);
            }
            int k = begin;
            for (; k + 3 < end; k += 4) {  // four independent gathers in flight
                int s0 = srcs[k];
                int s1 = srcs[k + 1];
                int s2 = srcs[k + 2];
                int s3 = srcs[k + 3];
                uint4 v0 = hsv[(size_t)s0 * 8 + c8];
                uint4 v1 = hsv[(size_t)s1 * 8 + c8];
                uint4 v2 = hsv[(size_t)s2 * 8 + c8];
                uint4 v3 = hsv[(size_t)s3 * 8 + c8];
                upadd(v0.x, alo.x, alo.y); upadd(v0.y, alo.z, alo.w);
                upadd(v0.z, ahi.x, ahi.y); upadd(v0.w, ahi.z, ahi.w);
                upadd(v1.x, alo.x, alo.y); upadd(v1.y, alo.z, alo.w);
                upadd(v1.z, ahi.x, ahi.y); upadd(v1.w, ahi.z, ahi.w);
                upadd(v2.x, alo.x, alo.y); upadd(v2.y, alo.z, alo.w);
                upadd(v2.z, ahi.x, ahi.y); upadd(v2.w, ahi.z, ahi.w);
                upadd(v3.x, alo.x, alo.y); upadd(v3.y, alo.z, alo.w);
                upadd(v3.z, ahi.x, ahi.y); upadd(v3.w, ahi.z, ahi.w);
            }
            for (; k < end; ++k) {
                int s = srcs[k];
                uint4 v = hsv[(size_t)s * 8 + c8];
                upadd(v.x, alo.x, alo.y); upadd(v.y, alo.z, alo.w);
                upadd(v.z, ahi.x, ahi.y); upadd(v.w, ahi.z, ahi.w);
            }
            float d = dinv[node];
            alo.x = fmaxf(alo.x * d + blo.x, 0.f);
            alo.y = fmaxf(alo.y * d + blo.y, 0.f);
            alo.z = fmaxf(alo.z * d + blo.z, 0.f);
            alo.w = fmaxf(alo.w * d + blo.w, 0.f);
            ahi.x = fmaxf(ahi.x * d + bhi.x, 0.f);
            ahi.y = fmaxf(ahi.y * d + bhi.y, 0.f);
            ahi.z = fmaxf(ahi.z * d + bhi.z, 0.f);
            ahi.w = fmaxf(ahi.w * d + bhi.w, 0.f);
        }
        float* row = &lds[g32 * 68 + c8 * 8];
        row[0] = alo.x; row[1] = alo.y; row[2] = alo.z; row[3] = alo.w;
        row[4] = ahi.x; row[5] = ahi.y; row[6] = ahi.z; row[7] = ahi.w;
        if (c8 == 0) bt[g32] = (node < N) ? batch[node] : -1;
        __syncthreads();
        if (tid < 64) {
            for (int g = 0; g < 32; ++g) {
                int bg = bt[g];
                if (bg < 0) break;  // tail (invalid nodes only at the end)
                if (bg != cur_g) {
                    if (cur_g >= 0) {
                        atomicAdd(&gsum[cur_g * D + ch], psum);
                        if (ch == 0) atomicAdd(&gcnt[cur_g], pcnt);
                    }
                    psum = 0.f; pcnt = 0.f; cur_g = bg;
                }
                psum += lds[g * 68 + ch];
                pcnt += 1.f;
            }
        }
        __syncthreads();
    }
    if (tid < 64 && cur_g >= 0) {
        atomicAdd(&gsum[cur_g * D + ch], psum);
        if (ch == 0) atomicAdd(&gcnt[cur_g], pcnt);
    }
}

// ---- head ----
__global__ void k_head(const float* __restrict__ gsum, const float* __restrict__ gcnt,
                       const float* __restrict__ W2, const float* __restrict__ b2,
                       float* __restrict__ out) {
    int g = threadIdx.x;
    if (g >= NG) return;
    float cnt = gcnt[g];
    cnt = cnt > 1.f ? cnt : 1.f;
    float inv = 1.f / cnt;
    float logits[NCLS];
#pragma unroll
    for (int c = 0; c < NCLS; ++c) logits[c] = b2[c];
    for (int k = 0; k < D; ++k) {
        float hk = gsum[g * D + k] * inv;
#pragma unroll
        for (int c = 0; c < NCLS; ++c) logits[c] += hk * W2[k * NCLS + c];
    }
    float m = logits[0];
#pragma unroll
    for (int c = 1; c < NCLS; ++c) m = fmaxf(m, logits[c]);
    float se = 0.f;
#pragma unroll
    for (int c = 0; c < NCLS; ++c) se += expf(logits[c] - m);
    float lse = m + logf(se);
#pragma unroll
    for (int c = 0; c < NCLS; ++c) out[g * NCLS + c] = logits[c] - lse;
}

static inline size_t pad256(size_t x) { return (x + 255) & ~(size_t)255; }

extern "C" void kernel_launch(void* const* d_in, const int* in_sizes, int n_in,
                              void* d_out, int out_size, void* d_ws, size_t ws_size,
                              hipStream_t stream) {
    const float* x     = (const float*)d_in[0];
    const int*   ei    = (const int*)d_in[1];   // [2, E]: src row then dst row
    const int*   batch = (const int*)d_in[2];
    const float* W1    = (const float*)d_in[3];
    const float* b1    = (const float*)d_in[4];
    const float* W2    = (const float*)d_in[5];
    const float* b2    = (const float*)d_in[6];
    float* out = (float*)d_out;

    const int N = in_sizes[0] / D;   // 100000
    const int E = in_sizes[1] / 2;   // 1000000
    const int NB = (N + 255) >> 8;   // 391 coarse buckets

    char* w = (char*)d_ws;
    ushort4* hs4      = (ushort4*)w; w += pad256((size_t)N * D * 2);
    float* dinv       = (float*)w;  w += pad256((size_t)N * 4);
    int*   rowptr     = (int*)w;    w += pad256((size_t)(N + 1) * 4);
    int*   srcs       = (int*)w;    w += pad256((size_t)E * 4);
    int*   e2p        = (int*)w;    w += pad256((size_t)E * 4);
    int*   blkCount   = (int*)w;    w += pad256((size_t)MAXNB * NBLK * 4);
    int*   bucketBase = (int*)w;    w += pad256((size_t)(MAXNB + 1) * 4);
    float* gsum       = (float*)w;  w += pad256((size_t)NG * D * 4);
    float* gcnt      = (float*)w;   w += pad256((size_t)NG * 4);

    const int* e_src = ei;
    const int* e_dst = ei + E;

    k_bcount<<<NBLK, 256, 0, stream>>>(e_dst, E, NB, blkCount, gsum, gcnt);
    k_bbase<<<1, 512, 0, stream>>>(blkCount, NB, E, bucketBase);
    k_bplace<<<NBLK, 256, 0, stream>>>(e_src, e_dst, E, NB, blkCount, e2p);
    k_csrdeg<<<NB, 256, 0, stream>>>(e2p, bucketBase, N, E, rowptr, dinv, srcs);

    k_xw1<<<(N + 63) / 64, 256, 0, stream>>>(x, W1, dinv, N, hs4);

    {
        int blocks = (N + 32 * TILES - 1) / (32 * TILES);
        k_gpool<<<blocks, 256, 0, stream>>>((const uint4*)hs4, dinv, rowptr, srcs,
                                            batch, b1, N, gsum, gcnt);
    }
    k_head<<<1, 128, 0, stream>>>(gsum, gcnt, W2, b2, out);
}